// Round 4
// baseline (6096.283 us; speedup 1.0000x reference)
//
#include <hip/hip_runtime.h>
#include <cstdint>
#include <cstddef>

#define B_ 2
#define S_ 2048
#define HID_ 2048
#define HK_ 16
#define HV_ 32
#define DK_ 128
#define DV_ 128
#define KEY_DIM_ 2048
#define VAL_DIM_ 4096
#define QKVZ_DIM_ 12288
#define BA_DIM_ 64
#define CONV_DIM_ 8192
#define EPS_ 1e-6f

__device__ __forceinline__ float silu_f(float x) { return x / (1.f + expf(-x)); }

__device__ __forceinline__ unsigned short f2bf(float x) {
    unsigned int u = __float_as_uint(x);
    u += 0x7FFF + ((u >> 16) & 1);   // round-to-nearest-even
    return (unsigned short)(u >> 16);
}
#define BF2F_LO(u) __uint_as_float((unsigned)(u) << 16)
#define BF2F_HI(u) __uint_as_float((unsigned)(u) & 0xFFFF0000u)

// ---------------------------------------------------------------------------
// GEMM NT: C[M,N] = A[M,K] * B[N,K]^T, fp32, 64x64 tile, BK=32, 256 threads,
// 4x4 micro-tile per thread. OUTBF16 selects fp32 or bf16 C-write.
// ---------------------------------------------------------------------------
#define BM 64
#define BN 64
#define BKK 32

template <int OUTBF16>
__global__ __launch_bounds__(256) void gemm_nt(const float* __restrict__ A,
                                               const float* __restrict__ Bm,
                                               void* __restrict__ Cv,
                                               int M, int N, int K) {
    __shared__ float As[BKK][BM + 4];
    __shared__ float Bs[BKK][BN + 4];
    const int tid = threadIdx.x;
    const int tx = tid & 15;        // N direction
    const int ty = tid >> 4;        // M direction
    const int bm = blockIdx.y, bn = blockIdx.x;
    const float* Ab = A + (size_t)bm * BM * K;
    const float* Bb = Bm + (size_t)bn * BN * K;
    const int lr = tid >> 2;          // 0..63 (row within tile)
    const int lc = (tid & 3) << 3;    // k offset 0,8,16,24

    float c[4][4] = {{0.f, 0.f, 0.f, 0.f}, {0.f, 0.f, 0.f, 0.f},
                     {0.f, 0.f, 0.f, 0.f}, {0.f, 0.f, 0.f, 0.f}};

    for (int k0 = 0; k0 < K; k0 += BKK) {
        const float4 a0 = *(const float4*)(Ab + (size_t)lr * K + k0 + lc);
        const float4 a1 = *(const float4*)(Ab + (size_t)lr * K + k0 + lc + 4);
        const float4 b0 = *(const float4*)(Bb + (size_t)lr * K + k0 + lc);
        const float4 b1 = *(const float4*)(Bb + (size_t)lr * K + k0 + lc + 4);
        __syncthreads();
        As[lc + 0][lr] = a0.x; As[lc + 1][lr] = a0.y;
        As[lc + 2][lr] = a0.z; As[lc + 3][lr] = a0.w;
        As[lc + 4][lr] = a1.x; As[lc + 5][lr] = a1.y;
        As[lc + 6][lr] = a1.z; As[lc + 7][lr] = a1.w;
        Bs[lc + 0][lr] = b0.x; Bs[lc + 1][lr] = b0.y;
        Bs[lc + 2][lr] = b0.z; Bs[lc + 3][lr] = b0.w;
        Bs[lc + 4][lr] = b1.x; Bs[lc + 5][lr] = b1.y;
        Bs[lc + 6][lr] = b1.z; Bs[lc + 7][lr] = b1.w;
        __syncthreads();
#pragma unroll
        for (int kk = 0; kk < BKK; ++kk) {
            const float4 Av = *(const float4*)&As[kk][ty << 2];
            const float4 Bv = *(const float4*)&Bs[kk][tx << 2];
            const float aa[4] = {Av.x, Av.y, Av.z, Av.w};
            const float bb[4] = {Bv.x, Bv.y, Bv.z, Bv.w};
#pragma unroll
            for (int i = 0; i < 4; ++i)
#pragma unroll
                for (int j = 0; j < 4; ++j)
                    c[i][j] = fmaf(aa[i], bb[j], c[i][j]);
        }
    }
    if (OUTBF16) {
        unsigned short* Cp = (unsigned short*)Cv +
                             (size_t)(bm * BM + (ty << 2)) * N + bn * BN +
                             (tx << 2);
#pragma unroll
        for (int i = 0; i < 4; ++i) {
            ushort4 o;
            o.x = f2bf(c[i][0]); o.y = f2bf(c[i][1]);
            o.z = f2bf(c[i][2]); o.w = f2bf(c[i][3]);
            *(ushort4*)(Cp + (size_t)i * N) = o;
        }
    } else {
        float* Cp = (float*)Cv + (size_t)(bm * BM + (ty << 2)) * N + bn * BN +
                    (tx << 2);
#pragma unroll
        for (int i = 0; i < 4; ++i) {
            *(float4*)(Cp + (size_t)i * N) =
                make_float4(c[i][0], c[i][1], c[i][2], c[i][3]);
        }
    }
}

// ---------------------------------------------------------------------------
// Causal depthwise conv (K=4) + SiLU. Reads q/k/v channels out of qkvz via the
// head-interleaved column map, writes bf16 mixed[B,S,8192] = [q | k | v].
// ---------------------------------------------------------------------------
__global__ __launch_bounds__(256) void conv_silu_kernel(
    const float* __restrict__ qkvz, const float* __restrict__ cw,
    unsigned short* __restrict__ mixed) {
    const int64_t idx = (int64_t)blockIdx.x * 256 + threadIdx.x; // B*S*CONV_DIM
    const int c = (int)(idx & (CONV_DIM_ - 1));
    const int64_t bs = idx >> 13;      // b*S + s
    const int s = (int)(bs & (S_ - 1));

    int col;
    if (c < KEY_DIM_) {
        col = ((c >> 7) * 768) + (c & 127);                       // q
    } else if (c < 2 * KEY_DIM_) {
        const int c2 = c - KEY_DIM_;
        col = ((c2 >> 7) * 768) + 128 + (c2 & 127);               // k
    } else {
        const int c3 = c - 2 * KEY_DIM_;
        col = ((c3 >> 8) * 768) + 256 + (c3 & 255);               // v
    }
    const float w0 = cw[c * 4 + 0], w1 = cw[c * 4 + 1];
    const float w2 = cw[c * 4 + 2], w3 = cw[c * 4 + 3];
    const float* xp = qkvz + bs * (int64_t)QKVZ_DIM_ + col;
    float acc = w3 * xp[0];
    if (s >= 1) acc = fmaf(w2, xp[-QKVZ_DIM_], acc);
    if (s >= 2) acc = fmaf(w1, xp[-2 * QKVZ_DIM_], acc);
    if (s >= 3) acc = fmaf(w0, xp[-3 * QKVZ_DIM_], acc);
    mixed[idx] = f2bf(silu_f(acc));
}

// ---------------------------------------------------------------------------
// Gate precompute: g = -exp(A_log)*softplus(a+dt_bias), beta = sigmoid(b)
// ba layout (B,S,HK,4) = [b0,b1,a0,a1] per k-head.
// ---------------------------------------------------------------------------
__global__ __launch_bounds__(256) void gate_kernel(
    const float* __restrict__ ba, const float* __restrict__ A_log,
    const float* __restrict__ dt_bias, float* __restrict__ gbuf,
    float* __restrict__ betabuf) {
    const int idx = blockIdx.x * 256 + threadIdx.x;   // B*S*HV
    const int hv = idx & (HV_ - 1);
    const int bs = idx >> 5;
    const int hk = hv >> 1, j = hv & 1;
    const float* p = ba + (size_t)bs * BA_DIM_ + hk * 4;
    const float bval = p[j];
    const float aval = p[2 + j];
    const float x = aval + dt_bias[hv];
    const float sp = (x > 20.f) ? x : log1pf(expf(x));
    gbuf[idx] = -expf(A_log[hv]) * sp;
    betabuf[idx] = 1.f / (1.f + expf(-bval));
}

// ---------------------------------------------------------------------------
// Gated delta rule sequential scan. One wave per (b, hv, dv-block-of-4).
// lane = dvi*16 + g ; each lane owns state rows [g*8, g*8+8) of column dv.
// All reductions are 16-lane shuffles (intra-wave): no LDS, no barriers.
// ---------------------------------------------------------------------------
__global__ __launch_bounds__(256) void delta_scan_kernel(
    const unsigned short* __restrict__ mixed, const float* __restrict__ gbuf,
    const float* __restrict__ betabuf, float* __restrict__ core) {
    const int wid = (blockIdx.x * 256 + threadIdx.x) >> 6;  // 0..2047
    const int lane = threadIdx.x & 63;
    const int dvb = wid & 31;
    const int hv = (wid >> 5) & 31;
    const int b = wid >> 10;
    const int g = lane & 15;
    const int dvi = lane >> 4;
    const int dv = (dvb << 2) + dvi;
    const int hk = hv >> 1;

    const unsigned short* qbase =
        mixed + (size_t)b * S_ * CONV_DIM_ + hk * DK_ + g * 8;
    const unsigned short* kbase = qbase + KEY_DIM_;
    const unsigned short* vbase =
        mixed + (size_t)b * S_ * CONV_DIM_ + 2 * KEY_DIM_ + hv * DV_ + dv;
    const float* gp = gbuf + (size_t)b * S_ * HV_ + hv;
    const float* bp = betabuf + (size_t)b * S_ * HV_ + hv;
    float* op = core + (size_t)b * S_ * VAL_DIM_ + hv * DV_ + dv;

    float st[8] = {0.f, 0.f, 0.f, 0.f, 0.f, 0.f, 0.f, 0.f};

    for (int s = 0; s < S_; ++s) {
        const size_t roff = (size_t)s * CONV_DIM_;
        const uint4 qw = *(const uint4*)(qbase + roff);
        const uint4 kw = *(const uint4*)(kbase + roff);
        const float vv = BF2F_LO(vbase[roff]);
        const float gg = gp[(size_t)s * HV_];
        const float bt = bp[(size_t)s * HV_];
        const float q_[8] = {BF2F_LO(qw.x), BF2F_HI(qw.x), BF2F_LO(qw.y),
                             BF2F_HI(qw.y), BF2F_LO(qw.z), BF2F_HI(qw.z),
                             BF2F_LO(qw.w), BF2F_HI(qw.w)};
        const float k_[8] = {BF2F_LO(kw.x), BF2F_HI(kw.x), BF2F_LO(kw.y),
                             BF2F_HI(kw.y), BF2F_LO(kw.z), BF2F_HI(kw.z),
                             BF2F_LO(kw.w), BF2F_HI(kw.w)};

        float qs = 0.f, ks = 0.f;
#pragma unroll
        for (int i = 0; i < 8; ++i) {
            qs = fmaf(q_[i], q_[i], qs);
            ks = fmaf(k_[i], k_[i], ks);
        }
#pragma unroll
        for (int m = 1; m < 16; m <<= 1) {
            qs += __shfl_xor(qs, m);
            ks += __shfl_xor(ks, m);
        }
        const float qsc = rsqrtf(qs + EPS_) * 0.08838834764831845f; // DK^-0.5
        const float ksc = rsqrtf(ks + EPS_);
        const float eg = expf(gg);

        float p = 0.f;
#pragma unroll
        for (int i = 0; i < 8; ++i) {
            st[i] *= eg;
            p = fmaf(k_[i] * ksc, st[i], p);
        }
#pragma unroll
        for (int m = 1; m < 16; m <<= 1) p += __shfl_xor(p, m);

        const float delta = (vv - p) * bt;

        float o = 0.f;
#pragma unroll
        for (int i = 0; i < 8; ++i) {
            st[i] = fmaf(k_[i] * ksc, delta, st[i]);
            o = fmaf(q_[i] * qsc, st[i], o);
        }
#pragma unroll
        for (int m = 1; m < 16; m <<= 1) o += __shfl_xor(o, m);

        if (g == 0) op[(size_t)s * VAL_DIM_] = o;
    }
}

// ---------------------------------------------------------------------------
// Gated RMSNorm (in-place on core). One wave per (b,s,hv) row of 128.
// z is taken from raw qkvz (not conv'd): col = (hv/2)*768 + 512 + (hv&1)*128.
// ---------------------------------------------------------------------------
__global__ __launch_bounds__(256) void rmsnorm_gate_kernel(
    float* __restrict__ core, const float* __restrict__ qkvz,
    const float* __restrict__ nw) {
    const int wid = (blockIdx.x * 256 + threadIdx.x) >> 6; // B*S*HV waves
    const int lane = threadIdx.x & 63;
    const int hv = wid & (HV_ - 1);
    const int64_t bs = wid >> 5;
    float* x = core + (size_t)bs * VAL_DIM_ + hv * DV_;
    const float x0 = x[lane];
    const float x1 = x[lane + 64];
    float ss = fmaf(x0, x0, x1 * x1);
#pragma unroll
    for (int m = 1; m < 64; m <<= 1) ss += __shfl_xor(ss, m);
    const float inv = rsqrtf(ss * (1.f / 128.f) + EPS_);
    const float* z =
        qkvz + (size_t)bs * QKVZ_DIM_ + (hv >> 1) * 768 + 512 + (hv & 1) * 128;
    x[lane] = x0 * inv * nw[lane] * silu_f(z[lane]);
    x[lane + 64] = x1 * inv * nw[lane + 64] * silu_f(z[lane + 64]);
}

// ---------------------------------------------------------------------------
extern "C" void kernel_launch(void* const* d_in, const int* in_sizes, int n_in,
                              void* d_out, int out_size, void* d_ws,
                              size_t ws_size, hipStream_t stream) {
    const float* hidden  = (const float*)d_in[0];  // (B,S,HID)
    const float* W_qkvz  = (const float*)d_in[1];  // (12288, 2048)
    const float* W_ba    = (const float*)d_in[2];  // (64, 2048)
    const float* conv_w  = (const float*)d_in[3];  // (8192,1,4)
    const float* dt_bias = (const float*)d_in[4];  // (32,)
    const float* A_log   = (const float*)d_in[5];  // (32,)
    const float* norm_w  = (const float*)d_in[6];  // (128,)
    const float* W_out   = (const float*)d_in[7];  // (2048, 4096)
    float* out = (float*)d_out;                    // (B,S,HID) fp32

    // workspace: 337.5 MB total (ran without fault in round 2)
    float* qkvz = (float*)d_ws;                                   // 201.3 MB
    unsigned short* mixed = (unsigned short*)(qkvz + 50331648);   //  67.1 MB
    float* core = (float*)(mixed + 33554432);                     //  67.1 MB
    float* ba = core + 16777216;                                  //   1.0 MB
    float* gbuf = ba + 262144;                                    //   0.5 MB
    float* betabuf = gbuf + 131072;                               //   0.5 MB

    const int MBS = B_ * S_;  // 4096

    // 1. qkvz = hidden @ W_qkvz^T   (4096 x 12288 x 2048)
    gemm_nt<0><<<dim3(QKVZ_DIM_ / BN, MBS / BM), 256, 0, stream>>>(
        hidden, W_qkvz, qkvz, MBS, QKVZ_DIM_, HID_);
    // 2. ba = hidden @ W_ba^T       (4096 x 64 x 2048)
    gemm_nt<0><<<dim3(BA_DIM_ / BN, MBS / BM), 256, 0, stream>>>(
        hidden, W_ba, ba, MBS, BA_DIM_, HID_);
    // 3. gates
    gate_kernel<<<(MBS * HV_) / 256, 256, 0, stream>>>(ba, A_log, dt_bias,
                                                       gbuf, betabuf);
    // 4. causal conv + silu -> mixed (bf16)
    conv_silu_kernel<<<(int)(((int64_t)MBS * CONV_DIM_) / 256), 256, 0,
                       stream>>>(qkvz, conv_w, mixed);
    // 5. gated delta rule scan -> core
    delta_scan_kernel<<<(B_ * HV_ * (DV_ / 4) * 64) / 256, 256, 0, stream>>>(
        mixed, gbuf, betabuf, core);
    // 6. gated rmsnorm (in place)
    rmsnorm_gate_kernel<<<(MBS * HV_ * 64) / 256, 256, 0, stream>>>(core, qkvz,
                                                                    norm_w);
    // 7. out = core @ W_out^T      (4096 x 2048 x 4096) -> fp32 out
    gemm_nt<0><<<dim3(HID_ / BN, MBS / BM), 256, 0, stream>>>(
        core, W_out, (void*)out, MBS, HID_, VAL_DIM_);
}

// Round 5
// 2408.253 us; speedup vs baseline: 2.5314x; 2.5314x over previous
//
#include <hip/hip_runtime.h>
#include <cstdint>
#include <cstddef>

#define B_ 2
#define S_ 2048
#define HID_ 2048
#define HK_ 16
#define HV_ 32
#define DK_ 128
#define DV_ 128
#define KEY_DIM_ 2048
#define VAL_DIM_ 4096
#define QKVZ_DIM_ 12288
#define BA_DIM_ 64
#define CONV_DIM_ 8192
#define EPS_ 1e-6f

typedef unsigned short bf16;
typedef __attribute__((ext_vector_type(8))) short bf16x8;
typedef __attribute__((ext_vector_type(4))) float f32x4;

__device__ __forceinline__ float silu_f(float x) { return x / (1.f + expf(-x)); }

__device__ __forceinline__ bf16 f2bf(float x) {
    unsigned int u = __float_as_uint(x);
    u += 0x7FFF + ((u >> 16) & 1);   // round-to-nearest-even
    return (bf16)(u >> 16);
}
__device__ __forceinline__ float bf2f(bf16 x) {
    return __uint_as_float((unsigned)x << 16);
}
#define BF2F_LO(u) __uint_as_float((unsigned)(u) << 16)
#define BF2F_HI(u) __uint_as_float((unsigned)(u) & 0xFFFF0000u)

typedef const __attribute__((address_space(1))) unsigned int cgu32;
typedef __attribute__((address_space(3))) unsigned int lsu32;
__device__ __forceinline__ void gld16(const void* g, void* l) {
    __builtin_amdgcn_global_load_lds((cgu32*)g, (lsu32*)l, 16, 0, 0);
}

// ---------------------------------------------------------------------------
// fp32 -> bf16 conversion, 4 elems/thread
// ---------------------------------------------------------------------------
__global__ __launch_bounds__(256) void f2bf_kernel(const float* __restrict__ in,
                                                   bf16* __restrict__ out) {
    const int64_t i = (int64_t)blockIdx.x * 256 + threadIdx.x;
    const float4 v = ((const float4*)in)[i];
    ushort4 o;
    o.x = f2bf(v.x); o.y = f2bf(v.y); o.z = f2bf(v.z); o.w = f2bf(v.w);
    ((ushort4*)out)[i] = o;
}

// ---------------------------------------------------------------------------
// bf16 MFMA GEMM NT: C[M,N] = A[M,K]*B[N,K]^T, fp32 accumulate.
// 128x128 tile, BK=32, 256 threads (4 waves, 2x2), 64x64 per wave,
// global_load_lds width-16 staging, 16x16x32 bf16 MFMA (m97 structure).
// ---------------------------------------------------------------------------
template <int OUTBF16>
__global__ __launch_bounds__(256) void gemm_mfma_nt(const bf16* __restrict__ A,
                                                    const bf16* __restrict__ Bm,
                                                    void* __restrict__ Cv,
                                                    int M, int N, int K) {
    __shared__ bf16 As[128 * 32];   // 8 KB
    __shared__ bf16 Bs[128 * 32];   // 8 KB
    const int tid = threadIdx.x;
    const int w = tid >> 6;         // wave 0..3
    const int l = tid & 63;
    const int bm = blockIdx.y, bn = blockIdx.x;

    // staging: lane l covers row (l>>2), k-chunk (l&3)*8 of a 16-row stripe
    const int srow = l >> 2;
    const int scol = (l & 3) << 3;
    const bf16* Ag = A + (size_t)(bm * 128 + w * 16 + srow) * K + scol;
    const bf16* Bg = Bm + (size_t)(bn * 128 + w * 16 + srow) * K + scol;
    bf16* Al = As + w * 16 * 32;    // wave-uniform LDS base
    bf16* Bl = Bs + w * 16 * 32;
    const size_t rstep = (size_t)64 * K;

    // compute: wave (w>>1, w&1) owns 64x64 output block
    const int wr = (w >> 1) * 64;
    const int wc = (w & 1) * 64;
    const int fl = l & 15;          // row (A) / col (B) within 16
    const int fk = (l >> 4) * 8;    // k offset

    f32x4 acc[4][4];
#pragma unroll
    for (int m = 0; m < 4; ++m)
#pragma unroll
        for (int n = 0; n < 4; ++n) acc[m][n] = (f32x4){0.f, 0.f, 0.f, 0.f};

    for (int k0 = 0; k0 < K; k0 += 32) {
        gld16(Ag + k0, Al);
        gld16(Ag + k0 + rstep, Al + 64 * 32);
        gld16(Bg + k0, Bl);
        gld16(Bg + k0 + rstep, Bl + 64 * 32);
        __syncthreads();   // drains vmcnt (async LDS loads) + lgkm

        bf16x8 af[4], bb[4];
#pragma unroll
        for (int m = 0; m < 4; ++m)
            af[m] = *(const bf16x8*)(As + (wr + m * 16 + fl) * 32 + fk);
#pragma unroll
        for (int n = 0; n < 4; ++n)
            bb[n] = *(const bf16x8*)(Bs + (wc + n * 16 + fl) * 32 + fk);
#pragma unroll
        for (int m = 0; m < 4; ++m)
#pragma unroll
            for (int n = 0; n < 4; ++n)
                acc[m][n] = __builtin_amdgcn_mfma_f32_16x16x32_bf16(
                    af[m], bb[n], acc[m][n], 0, 0, 0);
        __syncthreads();   // protect LDS before next stage
    }

    // epilogue: C/D map col=lane&15, row=(lane>>4)*4+r  [verified m89/m91]
    const int r0 = (l >> 4) * 2;  // helper below uses (l>>4)*4 + r
    (void)r0;
    if (OUTBF16) {
        bf16* C = (bf16*)Cv;
#pragma unroll
        for (int m = 0; m < 4; ++m)
#pragma unroll
            for (int n = 0; n < 4; ++n)
#pragma unroll
                for (int r = 0; r < 4; ++r) {
                    const int row = bm * 128 + wr + m * 16 + (l >> 4) * 4 + r;
                    const int col = bn * 128 + wc + n * 16 + fl;
                    C[(size_t)row * N + col] = f2bf(acc[m][n][r]);
                }
    } else {
        float* C = (float*)Cv;
#pragma unroll
        for (int m = 0; m < 4; ++m)
#pragma unroll
            for (int n = 0; n < 4; ++n)
#pragma unroll
                for (int r = 0; r < 4; ++r) {
                    const int row = bm * 128 + wr + m * 16 + (l >> 4) * 4 + r;
                    const int col = bn * 128 + wc + n * 16 + fl;
                    C[(size_t)row * N + col] = acc[m][n][r];
                }
    }
}

// ---------------------------------------------------------------------------
// fp32 vector GEMM (kept for the tiny ba projection, N=64)
// ---------------------------------------------------------------------------
#define BM 64
#define BN 64
#define BKK 32

__global__ __launch_bounds__(256) void gemm_nt_f32(const float* __restrict__ A,
                                                   const float* __restrict__ Bm,
                                                   float* __restrict__ C,
                                                   int M, int N, int K) {
    __shared__ float As[BKK][BM + 4];
    __shared__ float Bs[BKK][BN + 4];
    const int tid = threadIdx.x;
    const int tx = tid & 15;
    const int ty = tid >> 4;
    const int bm = blockIdx.y, bn = blockIdx.x;
    const float* Ab = A + (size_t)bm * BM * K;
    const float* Bb = Bm + (size_t)bn * BN * K;
    const int lr = tid >> 2;
    const int lc = (tid & 3) << 3;

    float c[4][4] = {{0.f, 0.f, 0.f, 0.f}, {0.f, 0.f, 0.f, 0.f},
                     {0.f, 0.f, 0.f, 0.f}, {0.f, 0.f, 0.f, 0.f}};

    for (int k0 = 0; k0 < K; k0 += BKK) {
        const float4 a0 = *(const float4*)(Ab + (size_t)lr * K + k0 + lc);
        const float4 a1 = *(const float4*)(Ab + (size_t)lr * K + k0 + lc + 4);
        const float4 b0 = *(const float4*)(Bb + (size_t)lr * K + k0 + lc);
        const float4 b1 = *(const float4*)(Bb + (size_t)lr * K + k0 + lc + 4);
        __syncthreads();
        As[lc + 0][lr] = a0.x; As[lc + 1][lr] = a0.y;
        As[lc + 2][lr] = a0.z; As[lc + 3][lr] = a0.w;
        As[lc + 4][lr] = a1.x; As[lc + 5][lr] = a1.y;
        As[lc + 6][lr] = a1.z; As[lc + 7][lr] = a1.w;
        Bs[lc + 0][lr] = b0.x; Bs[lc + 1][lr] = b0.y;
        Bs[lc + 2][lr] = b0.z; Bs[lc + 3][lr] = b0.w;
        Bs[lc + 4][lr] = b1.x; Bs[lc + 5][lr] = b1.y;
        Bs[lc + 6][lr] = b1.z; Bs[lc + 7][lr] = b1.w;
        __syncthreads();
#pragma unroll
        for (int kk = 0; kk < BKK; ++kk) {
            const float4 Av = *(const float4*)&As[kk][ty << 2];
            const float4 Bv = *(const float4*)&Bs[kk][tx << 2];
            const float aa[4] = {Av.x, Av.y, Av.z, Av.w};
            const float bb[4] = {Bv.x, Bv.y, Bv.z, Bv.w};
#pragma unroll
            for (int i = 0; i < 4; ++i)
#pragma unroll
                for (int j = 0; j < 4; ++j)
                    c[i][j] = fmaf(aa[i], bb[j], c[i][j]);
        }
    }
    float* Cp = C + (size_t)(bm * BM + (ty << 2)) * N + bn * BN + (tx << 2);
#pragma unroll
    for (int i = 0; i < 4; ++i)
        *(float4*)(Cp + (size_t)i * N) =
            make_float4(c[i][0], c[i][1], c[i][2], c[i][3]);
}

// ---------------------------------------------------------------------------
// Causal depthwise conv (K=4) + SiLU, bf16 qkvz -> bf16 mixed[B,S,8192]=[q|k|v]
// ---------------------------------------------------------------------------
__global__ __launch_bounds__(256) void conv_silu_kernel(
    const bf16* __restrict__ qkvz, const float* __restrict__ cw,
    bf16* __restrict__ mixed) {
    const int64_t idx = (int64_t)blockIdx.x * 256 + threadIdx.x;
    const int c = (int)(idx & (CONV_DIM_ - 1));
    const int64_t bs = idx >> 13;
    const int s = (int)(bs & (S_ - 1));

    int col;
    if (c < KEY_DIM_) {
        col = ((c >> 7) * 768) + (c & 127);                       // q
    } else if (c < 2 * KEY_DIM_) {
        const int c2 = c - KEY_DIM_;
        col = ((c2 >> 7) * 768) + 128 + (c2 & 127);               // k
    } else {
        const int c3 = c - 2 * KEY_DIM_;
        col = ((c3 >> 8) * 768) + 256 + (c3 & 255);               // v
    }
    const float w0 = cw[c * 4 + 0], w1 = cw[c * 4 + 1];
    const float w2 = cw[c * 4 + 2], w3 = cw[c * 4 + 3];
    const bf16* xp = qkvz + bs * (int64_t)QKVZ_DIM_ + col;
    float acc = w3 * bf2f(xp[0]);
    if (s >= 1) acc = fmaf(w2, bf2f(xp[-QKVZ_DIM_]), acc);
    if (s >= 2) acc = fmaf(w1, bf2f(xp[-2 * QKVZ_DIM_]), acc);
    if (s >= 3) acc = fmaf(w0, bf2f(xp[-3 * QKVZ_DIM_]), acc);
    mixed[idx] = f2bf(silu_f(acc));
}

// ---------------------------------------------------------------------------
// Gate precompute
// ---------------------------------------------------------------------------
__global__ __launch_bounds__(256) void gate_kernel(
    const float* __restrict__ ba, const float* __restrict__ A_log,
    const float* __restrict__ dt_bias, float* __restrict__ gbuf,
    float* __restrict__ betabuf) {
    const int idx = blockIdx.x * 256 + threadIdx.x;   // B*S*HV
    const int hv = idx & (HV_ - 1);
    const int bs = idx >> 5;
    const int hk = hv >> 1, j = hv & 1;
    const float* p = ba + (size_t)bs * BA_DIM_ + hk * 4;
    const float bval = p[j];
    const float aval = p[2 + j];
    const float x = aval + dt_bias[hv];
    const float sp = (x > 20.f) ? x : log1pf(expf(x));
    gbuf[idx] = -expf(A_log[hv]) * sp;
    betabuf[idx] = 1.f / (1.f + expf(-bval));
}

// ---------------------------------------------------------------------------
// Gated delta rule scan. One wave per (b, hv, dv-block-of-4); intra-wave
// 16-lane shuffle reductions; bf16 core out.
// ---------------------------------------------------------------------------
__global__ __launch_bounds__(256) void delta_scan_kernel(
    const bf16* __restrict__ mixed, const float* __restrict__ gbuf,
    const float* __restrict__ betabuf, bf16* __restrict__ core) {
    const int wid = (blockIdx.x * 256 + threadIdx.x) >> 6;  // 0..2047
    const int lane = threadIdx.x & 63;
    const int dvb = wid & 31;
    const int hv = (wid >> 5) & 31;
    const int b = wid >> 10;
    const int g = lane & 15;
    const int dvi = lane >> 4;
    const int dv = (dvb << 2) + dvi;
    const int hk = hv >> 1;

    const bf16* qbase = mixed + (size_t)b * S_ * CONV_DIM_ + hk * DK_ + g * 8;
    const bf16* kbase = qbase + KEY_DIM_;
    const bf16* vbase =
        mixed + (size_t)b * S_ * CONV_DIM_ + 2 * KEY_DIM_ + hv * DV_ + dv;
    const float* gp = gbuf + (size_t)b * S_ * HV_ + hv;
    const float* bp = betabuf + (size_t)b * S_ * HV_ + hv;
    bf16* op = core + (size_t)b * S_ * VAL_DIM_ + hv * DV_ + dv;

    float st[8] = {0.f, 0.f, 0.f, 0.f, 0.f, 0.f, 0.f, 0.f};

    for (int s = 0; s < S_; ++s) {
        const size_t roff = (size_t)s * CONV_DIM_;
        const uint4 qw = *(const uint4*)(qbase + roff);
        const uint4 kw = *(const uint4*)(kbase + roff);
        const float vv = bf2f(vbase[roff]);
        const float gg = gp[(size_t)s * HV_];
        const float bt = bp[(size_t)s * HV_];
        const float q_[8] = {BF2F_LO(qw.x), BF2F_HI(qw.x), BF2F_LO(qw.y),
                             BF2F_HI(qw.y), BF2F_LO(qw.z), BF2F_HI(qw.z),
                             BF2F_LO(qw.w), BF2F_HI(qw.w)};
        const float k_[8] = {BF2F_LO(kw.x), BF2F_HI(kw.x), BF2F_LO(kw.y),
                             BF2F_HI(kw.y), BF2F_LO(kw.z), BF2F_HI(kw.z),
                             BF2F_LO(kw.w), BF2F_HI(kw.w)};

        float qs = 0.f, ks = 0.f;
#pragma unroll
        for (int i = 0; i < 8; ++i) {
            qs = fmaf(q_[i], q_[i], qs);
            ks = fmaf(k_[i], k_[i], ks);
        }
#pragma unroll
        for (int m = 1; m < 16; m <<= 1) {
            qs += __shfl_xor(qs, m);
            ks += __shfl_xor(ks, m);
        }
        const float qsc = rsqrtf(qs + EPS_) * 0.08838834764831845f; // DK^-0.5
        const float ksc = rsqrtf(ks + EPS_);
        const float eg = expf(gg);

        float p = 0.f;
#pragma unroll
        for (int i = 0; i < 8; ++i) {
            st[i] *= eg;
            p = fmaf(k_[i] * ksc, st[i], p);
        }
#pragma unroll
        for (int m = 1; m < 16; m <<= 1) p += __shfl_xor(p, m);

        const float delta = (vv - p) * bt;

        float o = 0.f;
#pragma unroll
        for (int i = 0; i < 8; ++i) {
            st[i] = fmaf(k_[i] * ksc, delta, st[i]);
            o = fmaf(q_[i] * qsc, st[i], o);
        }
#pragma unroll
        for (int m = 1; m < 16; m <<= 1) o += __shfl_xor(o, m);

        if (g == 0) op[(size_t)s * VAL_DIM_] = f2bf(o);
    }
}

// ---------------------------------------------------------------------------
// Gated RMSNorm in-place on bf16 core; z from bf16 qkvz.
// ---------------------------------------------------------------------------
__global__ __launch_bounds__(256) void rmsnorm_gate_kernel(
    bf16* __restrict__ core, const bf16* __restrict__ qkvz,
    const float* __restrict__ nw) {
    const int wid = (blockIdx.x * 256 + threadIdx.x) >> 6;
    const int lane = threadIdx.x & 63;
    const int hv = wid & (HV_ - 1);
    const int64_t bs = wid >> 5;
    bf16* x = core + (size_t)bs * VAL_DIM_ + hv * DV_;
    const float x0 = bf2f(x[lane]);
    const float x1 = bf2f(x[lane + 64]);
    float ss = fmaf(x0, x0, x1 * x1);
#pragma unroll
    for (int m = 1; m < 64; m <<= 1) ss += __shfl_xor(ss, m);
    const float inv = rsqrtf(ss * (1.f / 128.f) + EPS_);
    const bf16* z =
        qkvz + (size_t)bs * QKVZ_DIM_ + (hv >> 1) * 768 + 512 + (hv & 1) * 128;
    x[lane] = f2bf(x0 * inv * nw[lane] * silu_f(bf2f(z[lane])));
    x[lane + 64] =
        f2bf(x1 * inv * nw[lane + 64] * silu_f(bf2f(z[lane + 64])));
}

// ---------------------------------------------------------------------------
extern "C" void kernel_launch(void* const* d_in, const int* in_sizes, int n_in,
                              void* d_out, int out_size, void* d_ws,
                              size_t ws_size, hipStream_t stream) {
    const float* hidden  = (const float*)d_in[0];  // (B,S,HID)
    const float* W_qkvz  = (const float*)d_in[1];  // (12288, 2048)
    const float* W_ba    = (const float*)d_in[2];  // (64, 2048)
    const float* conv_w  = (const float*)d_in[3];  // (8192,1,4)
    const float* dt_bias = (const float*)d_in[4];  // (32,)
    const float* A_log   = (const float*)d_in[5];  // (32,)
    const float* norm_w  = (const float*)d_in[6];  // (128,)
    const float* W_out   = (const float*)d_in[7];  // (2048, 4096)
    float* out = (float*)d_out;                    // (B,S,HID) fp32

    // workspace: 287.3 MB (< proven-good 337.5 MB)
    bf16* hidden_bf = (bf16*)d_ws;                        //  8,388,608 e
    bf16* Wq_bf  = hidden_bf + (size_t)8388608;           // 25,165,824 e
    bf16* Wo_bf  = Wq_bf + (size_t)25165824;              //  8,388,608 e
    bf16* qkvz   = Wo_bf + (size_t)8388608;               // 50,331,648 e
    bf16* mixed  = qkvz + (size_t)50331648;               // 33,554,432 e
    bf16* core   = mixed + (size_t)33554432;              // 16,777,216 e
    float* ba      = (float*)(core + (size_t)16777216);   //    262,144 f
    float* gbuf    = ba + 262144;                         //    131,072 f
    float* betabuf = gbuf + 131072;                       //    131,072 f

    const int MBS = B_ * S_;  // 4096

    // 0. fp32 -> bf16 operand conversion
    f2bf_kernel<<<8388608 / 1024, 256, 0, stream>>>(hidden, hidden_bf);
    f2bf_kernel<<<25165824 / 1024, 256, 0, stream>>>(W_qkvz, Wq_bf);
    f2bf_kernel<<<8388608 / 1024, 256, 0, stream>>>(W_out, Wo_bf);

    // 1. qkvz = hidden @ W_qkvz^T (4096 x 12288 x 2048), bf16 MFMA -> bf16
    gemm_mfma_nt<1><<<dim3(QKVZ_DIM_ / 128, MBS / 128), 256, 0, stream>>>(
        hidden_bf, Wq_bf, (void*)qkvz, MBS, QKVZ_DIM_, HID_);
    // 2. ba = hidden @ W_ba^T (4096 x 64 x 2048), fp32 vector
    gemm_nt_f32<<<dim3(BA_DIM_ / BN, MBS / BM), 256, 0, stream>>>(
        hidden, W_ba, ba, MBS, BA_DIM_, HID_);
    // 3. gates
    gate_kernel<<<(MBS * HV_) / 256, 256, 0, stream>>>(ba, A_log, dt_bias,
                                                       gbuf, betabuf);
    // 4. causal conv + silu -> mixed (bf16)
    conv_silu_kernel<<<(int)(((int64_t)MBS * CONV_DIM_) / 256), 256, 0,
                       stream>>>(qkvz, conv_w, mixed);
    // 5. gated delta rule scan -> core (bf16)
    delta_scan_kernel<<<(B_ * HV_ * (DV_ / 4) * 64) / 256, 256, 0, stream>>>(
        mixed, gbuf, betabuf, core);
    // 6. gated rmsnorm (in place on bf16 core)
    rmsnorm_gate_kernel<<<(MBS * HV_ * 64) / 256, 256, 0, stream>>>(core, qkvz,
                                                                    norm_w);
    // 7. out = core @ W_out^T (4096 x 2048 x 4096), bf16 MFMA -> fp32 out
    gemm_mfma_nt<0><<<dim3(HID_ / 128, MBS / 128), 256, 0, stream>>>(
        core, Wo_bf, (void*)out, MBS, HID_, VAL_DIM_);
}

// Round 6
// 1589.198 us; speedup vs baseline: 3.8361x; 1.5154x over previous
//
#include <hip/hip_runtime.h>
#include <cstdint>
#include <cstddef>

#define B_ 2
#define S_ 2048
#define HID_ 2048
#define HK_ 16
#define HV_ 32
#define DK_ 128
#define DV_ 128
#define KEY_DIM_ 2048
#define VAL_DIM_ 4096
#define QKVZ_DIM_ 12288
#define BA_DIM_ 64
#define CONV_DIM_ 8192
#define EPS_ 1e-6f

typedef unsigned short bf16;
typedef __attribute__((ext_vector_type(8))) short bf16x8;
typedef __attribute__((ext_vector_type(4))) float f32x4;

__device__ __forceinline__ float silu_f(float x) { return x / (1.f + expf(-x)); }

__device__ __forceinline__ bf16 f2bf(float x) {
    unsigned int u = __float_as_uint(x);
    u += 0x7FFF + ((u >> 16) & 1);   // round-to-nearest-even
    return (bf16)(u >> 16);
}
__device__ __forceinline__ float bf2f(bf16 x) {
    return __uint_as_float((unsigned)x << 16);
}
#define BF2F_LO(u) __uint_as_float((unsigned)(u) << 16)
#define BF2F_HI(u) __uint_as_float((unsigned)(u) & 0xFFFF0000u)

typedef const __attribute__((address_space(1))) unsigned int cgu32;
typedef __attribute__((address_space(3))) unsigned int lsu32;
__device__ __forceinline__ void gld16(const void* g, void* l) {
    __builtin_amdgcn_global_load_lds((cgu32*)g, (lsu32*)l, 16, 0, 0);
}

// DPP rotate-add: sum over each 16-lane row in ~2 VALU ops per step.
// row_ror:n ctrl = 0x120 | n.
template <int CTRL>
__device__ __forceinline__ float dpp_ror_add(float x) {
    const int t =
        __builtin_amdgcn_update_dpp(0, __float_as_int(x), CTRL, 0xF, 0xF, false);
    return x + __int_as_float(t);
}
__device__ __forceinline__ float row16_sum(float x) {
    x = dpp_ror_add<0x128>(x);  // ror 8
    x = dpp_ror_add<0x124>(x);  // ror 4
    x = dpp_ror_add<0x122>(x);  // ror 2
    x = dpp_ror_add<0x121>(x);  // ror 1
    return x;
}

// ---------------------------------------------------------------------------
// fp32 -> bf16 conversion, 4 elems/thread
// ---------------------------------------------------------------------------
__global__ __launch_bounds__(256) void f2bf_kernel(const float* __restrict__ in,
                                                   bf16* __restrict__ out) {
    const int64_t i = (int64_t)blockIdx.x * 256 + threadIdx.x;
    const float4 v = ((const float4*)in)[i];
    ushort4 o;
    o.x = f2bf(v.x); o.y = f2bf(v.y); o.z = f2bf(v.z); o.w = f2bf(v.w);
    ((ushort4*)out)[i] = o;
}

// ---------------------------------------------------------------------------
// bf16 MFMA GEMM NT (m97 structure, unchanged from round 5)
// ---------------------------------------------------------------------------
template <int OUTBF16>
__global__ __launch_bounds__(256) void gemm_mfma_nt(const bf16* __restrict__ A,
                                                    const bf16* __restrict__ Bm,
                                                    void* __restrict__ Cv,
                                                    int M, int N, int K) {
    __shared__ bf16 As[128 * 32];
    __shared__ bf16 Bs[128 * 32];
    const int tid = threadIdx.x;
    const int w = tid >> 6;
    const int l = tid & 63;
    const int bm = blockIdx.y, bn = blockIdx.x;

    const int srow = l >> 2;
    const int scol = (l & 3) << 3;
    const bf16* Ag = A + (size_t)(bm * 128 + w * 16 + srow) * K + scol;
    const bf16* Bg = Bm + (size_t)(bn * 128 + w * 16 + srow) * K + scol;
    bf16* Al = As + w * 16 * 32;
    bf16* Bl = Bs + w * 16 * 32;
    const size_t rstep = (size_t)64 * K;

    const int wr = (w >> 1) * 64;
    const int wc = (w & 1) * 64;
    const int fl = l & 15;
    const int fk = (l >> 4) * 8;

    f32x4 acc[4][4];
#pragma unroll
    for (int m = 0; m < 4; ++m)
#pragma unroll
        for (int n = 0; n < 4; ++n) acc[m][n] = (f32x4){0.f, 0.f, 0.f, 0.f};

    for (int k0 = 0; k0 < K; k0 += 32) {
        gld16(Ag + k0, Al);
        gld16(Ag + k0 + rstep, Al + 64 * 32);
        gld16(Bg + k0, Bl);
        gld16(Bg + k0 + rstep, Bl + 64 * 32);
        __syncthreads();

        bf16x8 af[4], bb[4];
#pragma unroll
        for (int m = 0; m < 4; ++m)
            af[m] = *(const bf16x8*)(As + (wr + m * 16 + fl) * 32 + fk);
#pragma unroll
        for (int n = 0; n < 4; ++n)
            bb[n] = *(const bf16x8*)(Bs + (wc + n * 16 + fl) * 32 + fk);
#pragma unroll
        for (int m = 0; m < 4; ++m)
#pragma unroll
            for (int n = 0; n < 4; ++n)
                acc[m][n] = __builtin_amdgcn_mfma_f32_16x16x32_bf16(
                    af[m], bb[n], acc[m][n], 0, 0, 0);
        __syncthreads();
    }

    if (OUTBF16) {
        bf16* C = (bf16*)Cv;
#pragma unroll
        for (int m = 0; m < 4; ++m)
#pragma unroll
            for (int n = 0; n < 4; ++n)
#pragma unroll
                for (int r = 0; r < 4; ++r) {
                    const int row = bm * 128 + wr + m * 16 + (l >> 4) * 4 + r;
                    const int col = bn * 128 + wc + n * 16 + fl;
                    C[(size_t)row * N + col] = f2bf(acc[m][n][r]);
                }
    } else {
        float* C = (float*)Cv;
#pragma unroll
        for (int m = 0; m < 4; ++m)
#pragma unroll
            for (int n = 0; n < 4; ++n)
#pragma unroll
                for (int r = 0; r < 4; ++r) {
                    const int row = bm * 128 + wr + m * 16 + (l >> 4) * 4 + r;
                    const int col = bn * 128 + wc + n * 16 + fl;
                    C[(size_t)row * N + col] = acc[m][n][r];
                }
    }
}

// ---------------------------------------------------------------------------
// fp32 vector GEMM (tiny ba projection)
// ---------------------------------------------------------------------------
#define BM 64
#define BN 64
#define BKK 32

__global__ __launch_bounds__(256) void gemm_nt_f32(const float* __restrict__ A,
                                                   const float* __restrict__ Bm,
                                                   float* __restrict__ C,
                                                   int M, int N, int K) {
    __shared__ float As[BKK][BM + 4];
    __shared__ float Bs[BKK][BN + 4];
    const int tid = threadIdx.x;
    const int tx = tid & 15;
    const int ty = tid >> 4;
    const int bm = blockIdx.y, bn = blockIdx.x;
    const float* Ab = A + (size_t)bm * BM * K;
    const float* Bb = Bm + (size_t)bn * BN * K;
    const int lr = tid >> 2;
    const int lc = (tid & 3) << 3;

    float c[4][4] = {{0.f, 0.f, 0.f, 0.f}, {0.f, 0.f, 0.f, 0.f},
                     {0.f, 0.f, 0.f, 0.f}, {0.f, 0.f, 0.f, 0.f}};

    for (int k0 = 0; k0 < K; k0 += BKK) {
        const float4 a0 = *(const float4*)(Ab + (size_t)lr * K + k0 + lc);
        const float4 a1 = *(const float4*)(Ab + (size_t)lr * K + k0 + lc + 4);
        const float4 b0 = *(const float4*)(Bb + (size_t)lr * K + k0 + lc);
        const float4 b1 = *(const float4*)(Bb + (size_t)lr * K + k0 + lc + 4);
        __syncthreads();
        As[lc + 0][lr] = a0.x; As[lc + 1][lr] = a0.y;
        As[lc + 2][lr] = a0.z; As[lc + 3][lr] = a0.w;
        As[lc + 4][lr] = a1.x; As[lc + 5][lr] = a1.y;
        As[lc + 6][lr] = a1.z; As[lc + 7][lr] = a1.w;
        Bs[lc + 0][lr] = b0.x; Bs[lc + 1][lr] = b0.y;
        Bs[lc + 2][lr] = b0.z; Bs[lc + 3][lr] = b0.w;
        Bs[lc + 4][lr] = b1.x; Bs[lc + 5][lr] = b1.y;
        Bs[lc + 6][lr] = b1.z; Bs[lc + 7][lr] = b1.w;
        __syncthreads();
#pragma unroll
        for (int kk = 0; kk < BKK; ++kk) {
            const float4 Av = *(const float4*)&As[kk][ty << 2];
            const float4 Bv = *(const float4*)&Bs[kk][tx << 2];
            const float aa[4] = {Av.x, Av.y, Av.z, Av.w};
            const float bb[4] = {Bv.x, Bv.y, Bv.z, Bv.w};
#pragma unroll
            for (int i = 0; i < 4; ++i)
#pragma unroll
                for (int j = 0; j < 4; ++j)
                    c[i][j] = fmaf(aa[i], bb[j], c[i][j]);
        }
    }
    float* Cp = C + (size_t)(bm * BM + (ty << 2)) * N + bn * BN + (tx << 2);
#pragma unroll
    for (int i = 0; i < 4; ++i)
        *(float4*)(Cp + (size_t)i * N) =
            make_float4(c[i][0], c[i][1], c[i][2], c[i][3]);
}

// ---------------------------------------------------------------------------
// Causal depthwise conv (K=4) + SiLU, bf16 qkvz -> bf16 mixed[B,S,8192]
// ---------------------------------------------------------------------------
__global__ __launch_bounds__(256) void conv_silu_kernel(
    const bf16* __restrict__ qkvz, const float* __restrict__ cw,
    bf16* __restrict__ mixed) {
    const int64_t idx = (int64_t)blockIdx.x * 256 + threadIdx.x;
    const int c = (int)(idx & (CONV_DIM_ - 1));
    const int64_t bs = idx >> 13;
    const int s = (int)(bs & (S_ - 1));

    int col;
    if (c < KEY_DIM_) {
        col = ((c >> 7) * 768) + (c & 127);                       // q
    } else if (c < 2 * KEY_DIM_) {
        const int c2 = c - KEY_DIM_;
        col = ((c2 >> 7) * 768) + 128 + (c2 & 127);               // k
    } else {
        const int c3 = c - 2 * KEY_DIM_;
        col = ((c3 >> 8) * 768) + 256 + (c3 & 255);               // v
    }
    const float w0 = cw[c * 4 + 0], w1 = cw[c * 4 + 1];
    const float w2 = cw[c * 4 + 2], w3 = cw[c * 4 + 3];
    const bf16* xp = qkvz + bs * (int64_t)QKVZ_DIM_ + col;
    float acc = w3 * bf2f(xp[0]);
    if (s >= 1) acc = fmaf(w2, bf2f(xp[-QKVZ_DIM_]), acc);
    if (s >= 2) acc = fmaf(w1, bf2f(xp[-2 * QKVZ_DIM_]), acc);
    if (s >= 3) acc = fmaf(w0, bf2f(xp[-3 * QKVZ_DIM_]), acc);
    mixed[idx] = f2bf(silu_f(acc));
}

// ---------------------------------------------------------------------------
// Pre-normalize q/k rows of mixed in place: q *= DK^-0.5/||q||, k *= 1/||k||.
// One wave per (b,s,hk); lane covers 2 elems of each row.
// ---------------------------------------------------------------------------
__global__ __launch_bounds__(256) void normalize_qk_kernel(
    bf16* __restrict__ mixed) {
    const int wid = (blockIdx.x * 256 + threadIdx.x) >> 6;  // B*S*HK
    const int lane = threadIdx.x & 63;
    const int hk = wid & (HK_ - 1);
    const int64_t bs = wid >> 4;
    bf16* qp = mixed + bs * CONV_DIM_ + hk * DK_ + lane * 2;
    bf16* kp = qp + KEY_DIM_;
    const unsigned qw = *(const unsigned*)qp;
    const unsigned kw = *(const unsigned*)kp;
    const float q0 = BF2F_LO(qw), q1 = BF2F_HI(qw);
    const float k0 = BF2F_LO(kw), k1 = BF2F_HI(kw);
    float qs = fmaf(q0, q0, q1 * q1);
    float ks = fmaf(k0, k0, k1 * k1);
#pragma unroll
    for (int m = 1; m < 64; m <<= 1) {
        qs += __shfl_xor(qs, m);
        ks += __shfl_xor(ks, m);
    }
    const float qsc = rsqrtf(qs + EPS_) * 0.08838834764831845f;  // DK^-0.5
    const float ksc = rsqrtf(ks + EPS_);
    ushort2 oq, ok;
    oq.x = f2bf(q0 * qsc); oq.y = f2bf(q1 * qsc);
    ok.x = f2bf(k0 * ksc); ok.y = f2bf(k1 * ksc);
    *(ushort2*)qp = oq;
    *(ushort2*)kp = ok;
}

// ---------------------------------------------------------------------------
// Gate precompute: egbuf = exp(g), betabuf = sigmoid(b)
// ---------------------------------------------------------------------------
__global__ __launch_bounds__(256) void gate_kernel(
    const float* __restrict__ ba, const float* __restrict__ A_log,
    const float* __restrict__ dt_bias, float* __restrict__ egbuf,
    float* __restrict__ betabuf) {
    const int idx = blockIdx.x * 256 + threadIdx.x;   // B*S*HV
    const int hv = idx & (HV_ - 1);
    const int bs = idx >> 5;
    const int hk = hv >> 1, j = hv & 1;
    const float* p = ba + (size_t)bs * BA_DIM_ + hk * 4;
    const float bval = p[j];
    const float aval = p[2 + j];
    const float x = aval + dt_bias[hv];
    const float sp = (x > 20.f) ? x : log1pf(expf(x));
    egbuf[idx] = expf(-expf(A_log[hv]) * sp);
    betabuf[idx] = 1.f / (1.f + expf(-bval));
}

// ---------------------------------------------------------------------------
// Gated delta rule scan, DPP edition. One wave per (b, hv, dv-block-of-4).
// q/k pre-normalized; eg pre-exp'd. Reduces via DPP row_ror adds (no LDS).
// Distance-1 prefetch of next step's operands.
// ---------------------------------------------------------------------------
__global__ __launch_bounds__(256) void delta_scan_kernel(
    const bf16* __restrict__ mixed, const float* __restrict__ egbuf,
    const float* __restrict__ betabuf, bf16* __restrict__ core) {
    const int wid = (blockIdx.x * 256 + threadIdx.x) >> 6;  // 0..2047
    const int lane = threadIdx.x & 63;
    const int dvb = wid & 31;
    const int hv = (wid >> 5) & 31;
    const int b = wid >> 10;
    const int g = lane & 15;
    const int dvi = lane >> 4;
    const int dv = (dvb << 2) + dvi;
    const int hk = hv >> 1;

    const bf16* qbase = mixed + (size_t)b * S_ * CONV_DIM_ + hk * DK_ + g * 8;
    const bf16* kbase = qbase + KEY_DIM_;
    const bf16* vbase =
        mixed + (size_t)b * S_ * CONV_DIM_ + 2 * KEY_DIM_ + hv * DV_ + dv;
    const float* egp = egbuf + (size_t)b * S_ * HV_ + hv;
    const float* bp = betabuf + (size_t)b * S_ * HV_ + hv;
    bf16* op = core + (size_t)b * S_ * VAL_DIM_ + hv * DV_ + dv;

    float st[8] = {0.f, 0.f, 0.f, 0.f, 0.f, 0.f, 0.f, 0.f};

    // prefetch s=0
    uint4 qw = *(const uint4*)qbase;
    uint4 kw = *(const uint4*)kbase;
    float vv = bf2f(vbase[0]);
    float eg = egp[0];
    float bt = bp[0];

    for (int s = 0; s < S_; ++s) {
        // prefetch s+1 (1-row overread at the end stays inside d_ws)
        const size_t roff_n = (size_t)(s + 1) * CONV_DIM_;
        const uint4 qw_n = *(const uint4*)(qbase + roff_n);
        const uint4 kw_n = *(const uint4*)(kbase + roff_n);
        const float vv_n = bf2f(vbase[roff_n]);
        const float eg_n = egp[(size_t)(s + 1) * HV_];
        const float bt_n = bp[(size_t)(s + 1) * HV_];

        const float q_[8] = {BF2F_LO(qw.x), BF2F_HI(qw.x), BF2F_LO(qw.y),
                             BF2F_HI(qw.y), BF2F_LO(qw.z), BF2F_HI(qw.z),
                             BF2F_LO(qw.w), BF2F_HI(qw.w)};
        const float k_[8] = {BF2F_LO(kw.x), BF2F_HI(kw.x), BF2F_LO(kw.y),
                             BF2F_HI(kw.y), BF2F_LO(kw.z), BF2F_HI(kw.z),
                             BF2F_LO(kw.w), BF2F_HI(kw.w)};

        // st *= eg;  p = <k, st>  (two accumulator chains)
        float p0 = 0.f, p1 = 0.f;
#pragma unroll
        for (int i = 0; i < 4; ++i) {
            st[i] *= eg;
            p0 = fmaf(k_[i], st[i], p0);
        }
#pragma unroll
        for (int i = 4; i < 8; ++i) {
            st[i] *= eg;
            p1 = fmaf(k_[i], st[i], p1);
        }
        const float p = row16_sum(p0 + p1);
        const float delta = (vv - p) * bt;

        float o0 = 0.f, o1 = 0.f;
#pragma unroll
        for (int i = 0; i < 4; ++i) {
            st[i] = fmaf(k_[i], delta, st[i]);
            o0 = fmaf(q_[i], st[i], o0);
        }
#pragma unroll
        for (int i = 4; i < 8; ++i) {
            st[i] = fmaf(k_[i], delta, st[i]);
            o1 = fmaf(q_[i], st[i], o1);
        }
        const float o = row16_sum(o0 + o1);

        if (g == 0) op[(size_t)s * VAL_DIM_] = f2bf(o);

        qw = qw_n; kw = kw_n; vv = vv_n; eg = eg_n; bt = bt_n;
    }
}

// ---------------------------------------------------------------------------
// Gated RMSNorm in-place on bf16 core; z from bf16 qkvz.
// ---------------------------------------------------------------------------
__global__ __launch_bounds__(256) void rmsnorm_gate_kernel(
    bf16* __restrict__ core, const bf16* __restrict__ qkvz,
    const float* __restrict__ nw) {
    const int wid = (blockIdx.x * 256 + threadIdx.x) >> 6;
    const int lane = threadIdx.x & 63;
    const int hv = wid & (HV_ - 1);
    const int64_t bs = wid >> 5;
    bf16* x = core + (size_t)bs * VAL_DIM_ + hv * DV_;
    const float x0 = bf2f(x[lane]);
    const float x1 = bf2f(x[lane + 64]);
    float ss = fmaf(x0, x0, x1 * x1);
#pragma unroll
    for (int m = 1; m < 64; m <<= 1) ss += __shfl_xor(ss, m);
    const float inv = rsqrtf(ss * (1.f / 128.f) + EPS_);
    const bf16* z =
        qkvz + (size_t)bs * QKVZ_DIM_ + (hv >> 1) * 768 + 512 + (hv & 1) * 128;
    x[lane] = f2bf(x0 * inv * nw[lane] * silu_f(bf2f(z[lane])));
    x[lane + 64] =
        f2bf(x1 * inv * nw[lane + 64] * silu_f(bf2f(z[lane + 64])));
}

// ---------------------------------------------------------------------------
extern "C" void kernel_launch(void* const* d_in, const int* in_sizes, int n_in,
                              void* d_out, int out_size, void* d_ws,
                              size_t ws_size, hipStream_t stream) {
    const float* hidden  = (const float*)d_in[0];
    const float* W_qkvz  = (const float*)d_in[1];
    const float* W_ba    = (const float*)d_in[2];
    const float* conv_w  = (const float*)d_in[3];
    const float* dt_bias = (const float*)d_in[4];
    const float* A_log   = (const float*)d_in[5];
    const float* norm_w  = (const float*)d_in[6];
    const float* W_out   = (const float*)d_in[7];
    float* out = (float*)d_out;

    // workspace: 287.3 MB used (< proven-good 337.5 MB)
    bf16* hidden_bf = (bf16*)d_ws;                        //  8,388,608 e
    bf16* Wq_bf  = hidden_bf + (size_t)8388608;           // 25,165,824 e
    bf16* Wo_bf  = Wq_bf + (size_t)25165824;              //  8,388,608 e
    bf16* qkvz   = Wo_bf + (size_t)8388608;               // 50,331,648 e
    bf16* mixed  = qkvz + (size_t)50331648;               // 33,554,432 e
    bf16* core   = mixed + (size_t)33554432;              // 16,777,216 e
    float* ba      = (float*)(core + (size_t)16777216);   //    262,144 f
    float* egbuf   = ba + 262144;                         //    131,072 f
    float* betabuf = egbuf + 131072;                      //    131,072 f

    const int MBS = B_ * S_;  // 4096

    // 0. fp32 -> bf16 operand conversion
    f2bf_kernel<<<8388608 / 1024, 256, 0, stream>>>(hidden, hidden_bf);
    f2bf_kernel<<<25165824 / 1024, 256, 0, stream>>>(W_qkvz, Wq_bf);
    f2bf_kernel<<<8388608 / 1024, 256, 0, stream>>>(W_out, Wo_bf);

    // 1. qkvz = hidden @ W_qkvz^T (bf16 MFMA)
    gemm_mfma_nt<1><<<dim3(QKVZ_DIM_ / 128, MBS / 128), 256, 0, stream>>>(
        hidden_bf, Wq_bf, (void*)qkvz, MBS, QKVZ_DIM_, HID_);
    // 2. ba = hidden @ W_ba^T (fp32 vector)
    gemm_nt_f32<<<dim3(BA_DIM_ / BN, MBS / BM), 256, 0, stream>>>(
        hidden, W_ba, ba, MBS, BA_DIM_, HID_);
    // 3. gates (eg = exp(g))
    gate_kernel<<<(MBS * HV_) / 256, 256, 0, stream>>>(ba, A_log, dt_bias,
                                                       egbuf, betabuf);
    // 4. causal conv + silu -> mixed (bf16)
    conv_silu_kernel<<<(int)(((int64_t)MBS * CONV_DIM_) / 256), 256, 0,
                       stream>>>(qkvz, conv_w, mixed);
    // 4b. pre-normalize q/k in place
    normalize_qk_kernel<<<(MBS * HK_ * 64) / 256, 256, 0, stream>>>(mixed);
    // 5. gated delta rule scan -> core (bf16)
    delta_scan_kernel<<<(B_ * HV_ * (DV_ / 4) * 64) / 256, 256, 0, stream>>>(
        mixed, egbuf, betabuf, core);
    // 6. gated rmsnorm (in place on bf16 core)
    rmsnorm_gate_kernel<<<(MBS * HV_ * 64) / 256, 256, 0, stream>>>(core, qkvz,
                                                                    norm_w);
    // 7. out = core @ W_out^T (bf16 MFMA -> fp32 out)
    gemm_mfma_nt<0><<<dim3(HID_ / 128, MBS / 128), 256, 0, stream>>>(
        core, Wo_bf, (void*)out, MBS, HID_, VAL_DIM_);
}

// Round 7
// 1405.027 us; speedup vs baseline: 4.3389x; 1.1311x over previous
//
#include <hip/hip_runtime.h>
#include <cstdint>
#include <cstddef>

#define B_ 2
#define S_ 2048
#define HID_ 2048
#define HK_ 16
#define HV_ 32
#define DK_ 128
#define DV_ 128
#define KEY_DIM_ 2048
#define VAL_DIM_ 4096
#define QKVZ_DIM_ 12288
#define BA_DIM_ 64
#define CONV_DIM_ 8192
#define EPS_ 1e-6f

typedef unsigned short bf16;
typedef __attribute__((ext_vector_type(8))) short bf16x8;
typedef __attribute__((ext_vector_type(4))) float f32x4;
typedef __attribute__((ext_vector_type(2))) float f32x2;

__device__ __forceinline__ float silu_f(float x) { return x / (1.f + expf(-x)); }

__device__ __forceinline__ bf16 f2bf(float x) {
    unsigned int u = __float_as_uint(x);
    u += 0x7FFF + ((u >> 16) & 1);   // round-to-nearest-even
    return (bf16)(u >> 16);
}
__device__ __forceinline__ float bf2f(bf16 x) {
    return __uint_as_float((unsigned)x << 16);
}
#define BF2F_LO(u) __uint_as_float((unsigned)(u) << 16)
#define BF2F_HI(u) __uint_as_float((unsigned)(u) & 0xFFFF0000u)

typedef const __attribute__((address_space(1))) unsigned int cgu32;
typedef __attribute__((address_space(3))) unsigned int lsu32;
__device__ __forceinline__ void gld16(const void* g, void* l) {
    __builtin_amdgcn_global_load_lds((cgu32*)g, (lsu32*)l, 16, 0, 0);
}

// ---- packed fp32 math (VOP3P, gfx90a+) ------------------------------------
__device__ __forceinline__ f32x2 pk_mul(f32x2 a, f32x2 b) {
    f32x2 d;
    asm("v_pk_mul_f32 %0, %1, %2" : "=v"(d) : "v"(a), "v"(b));
    return d;
}
__device__ __forceinline__ f32x2 pk_fma(f32x2 a, f32x2 b, f32x2 c) {
    f32x2 d;
    asm("v_pk_fma_f32 %0, %1, %2, %3" : "=v"(d) : "v"(a), "v"(b), "v"(c));
    return d;
}
__device__ __forceinline__ f32x2 pk_add(f32x2 a, f32x2 b) {
    f32x2 d;
    asm("v_pk_add_f32 %0, %1, %2" : "=v"(d) : "v"(a), "v"(b));
    return d;
}

// DPP rotate-add: sum over each 16-lane row. row_ror:n ctrl = 0x120 | n.
template <int CTRL>
__device__ __forceinline__ float dpp_ror_add(float x) {
    const int t =
        __builtin_amdgcn_update_dpp(0, __float_as_int(x), CTRL, 0xF, 0xF, false);
    return x + __int_as_float(t);
}
__device__ __forceinline__ float row16_sum(float x) {
    x = dpp_ror_add<0x128>(x);
    x = dpp_ror_add<0x124>(x);
    x = dpp_ror_add<0x122>(x);
    x = dpp_ror_add<0x121>(x);
    return x;
}

// ---------------------------------------------------------------------------
// fp32 -> bf16 conversion, 4 elems/thread
// ---------------------------------------------------------------------------
__global__ __launch_bounds__(256) void f2bf_kernel(const float* __restrict__ in,
                                                   bf16* __restrict__ out) {
    const int64_t i = (int64_t)blockIdx.x * 256 + threadIdx.x;
    const float4 v = ((const float4*)in)[i];
    ushort4 o;
    o.x = f2bf(v.x); o.y = f2bf(v.y); o.z = f2bf(v.z); o.w = f2bf(v.w);
    ((ushort4*)out)[i] = o;
}

// ---------------------------------------------------------------------------
// bf16 MFMA GEMM NT (m97 structure, unchanged)
// ---------------------------------------------------------------------------
template <int OUTBF16>
__global__ __launch_bounds__(256) void gemm_mfma_nt(const bf16* __restrict__ A,
                                                    const bf16* __restrict__ Bm,
                                                    void* __restrict__ Cv,
                                                    int M, int N, int K) {
    __shared__ bf16 As[128 * 32];
    __shared__ bf16 Bs[128 * 32];
    const int tid = threadIdx.x;
    const int w = tid >> 6;
    const int l = tid & 63;
    const int bm = blockIdx.y, bn = blockIdx.x;

    const int srow = l >> 2;
    const int scol = (l & 3) << 3;
    const bf16* Ag = A + (size_t)(bm * 128 + w * 16 + srow) * K + scol;
    const bf16* Bg = Bm + (size_t)(bn * 128 + w * 16 + srow) * K + scol;
    bf16* Al = As + w * 16 * 32;
    bf16* Bl = Bs + w * 16 * 32;
    const size_t rstep = (size_t)64 * K;

    const int wr = (w >> 1) * 64;
    const int wc = (w & 1) * 64;
    const int fl = l & 15;
    const int fk = (l >> 4) * 8;

    f32x4 acc[4][4];
#pragma unroll
    for (int m = 0; m < 4; ++m)
#pragma unroll
        for (int n = 0; n < 4; ++n) acc[m][n] = (f32x4){0.f, 0.f, 0.f, 0.f};

    for (int k0 = 0; k0 < K; k0 += 32) {
        gld16(Ag + k0, Al);
        gld16(Ag + k0 + rstep, Al + 64 * 32);
        gld16(Bg + k0, Bl);
        gld16(Bg + k0 + rstep, Bl + 64 * 32);
        __syncthreads();

        bf16x8 af[4], bb[4];
#pragma unroll
        for (int m = 0; m < 4; ++m)
            af[m] = *(const bf16x8*)(As + (wr + m * 16 + fl) * 32 + fk);
#pragma unroll
        for (int n = 0; n < 4; ++n)
            bb[n] = *(const bf16x8*)(Bs + (wc + n * 16 + fl) * 32 + fk);
#pragma unroll
        for (int m = 0; m < 4; ++m)
#pragma unroll
            for (int n = 0; n < 4; ++n)
                acc[m][n] = __builtin_amdgcn_mfma_f32_16x16x32_bf16(
                    af[m], bb[n], acc[m][n], 0, 0, 0);
        __syncthreads();
    }

    if (OUTBF16) {
        bf16* C = (bf16*)Cv;
#pragma unroll
        for (int m = 0; m < 4; ++m)
#pragma unroll
            for (int n = 0; n < 4; ++n)
#pragma unroll
                for (int r = 0; r < 4; ++r) {
                    const int row = bm * 128 + wr + m * 16 + (l >> 4) * 4 + r;
                    const int col = bn * 128 + wc + n * 16 + fl;
                    C[(size_t)row * N + col] = f2bf(acc[m][n][r]);
                }
    } else {
        float* C = (float*)Cv;
#pragma unroll
        for (int m = 0; m < 4; ++m)
#pragma unroll
            for (int n = 0; n < 4; ++n)
#pragma unroll
                for (int r = 0; r < 4; ++r) {
                    const int row = bm * 128 + wr + m * 16 + (l >> 4) * 4 + r;
                    const int col = bn * 128 + wc + n * 16 + fl;
                    C[(size_t)row * N + col] = acc[m][n][r];
                }
    }
}

// ---------------------------------------------------------------------------
// fp32 vector GEMM (tiny ba projection)
// ---------------------------------------------------------------------------
#define BM 64
#define BN 64
#define BKK 32

__global__ __launch_bounds__(256) void gemm_nt_f32(const float* __restrict__ A,
                                                   const float* __restrict__ Bm,
                                                   float* __restrict__ C,
                                                   int M, int N, int K) {
    __shared__ float As[BKK][BM + 4];
    __shared__ float Bs[BKK][BN + 4];
    const int tid = threadIdx.x;
    const int tx = tid & 15;
    const int ty = tid >> 4;
    const int bm = blockIdx.y, bn = blockIdx.x;
    const float* Ab = A + (size_t)bm * BM * K;
    const float* Bb = Bm + (size_t)bn * BN * K;
    const int lr = tid >> 2;
    const int lc = (tid & 3) << 3;

    float c[4][4] = {{0.f, 0.f, 0.f, 0.f}, {0.f, 0.f, 0.f, 0.f},
                     {0.f, 0.f, 0.f, 0.f}, {0.f, 0.f, 0.f, 0.f}};

    for (int k0 = 0; k0 < K; k0 += BKK) {
        const float4 a0 = *(const float4*)(Ab + (size_t)lr * K + k0 + lc);
        const float4 a1 = *(const float4*)(Ab + (size_t)lr * K + k0 + lc + 4);
        const float4 b0 = *(const float4*)(Bb + (size_t)lr * K + k0 + lc);
        const float4 b1 = *(const float4*)(Bb + (size_t)lr * K + k0 + lc + 4);
        __syncthreads();
        As[lc + 0][lr] = a0.x; As[lc + 1][lr] = a0.y;
        As[lc + 2][lr] = a0.z; As[lc + 3][lr] = a0.w;
        As[lc + 4][lr] = a1.x; As[lc + 5][lr] = a1.y;
        As[lc + 6][lr] = a1.z; As[lc + 7][lr] = a1.w;
        Bs[lc + 0][lr] = b0.x; Bs[lc + 1][lr] = b0.y;
        Bs[lc + 2][lr] = b0.z; Bs[lc + 3][lr] = b0.w;
        Bs[lc + 4][lr] = b1.x; Bs[lc + 5][lr] = b1.y;
        Bs[lc + 6][lr] = b1.z; Bs[lc + 7][lr] = b1.w;
        __syncthreads();
#pragma unroll
        for (int kk = 0; kk < BKK; ++kk) {
            const float4 Av = *(const float4*)&As[kk][ty << 2];
            const float4 Bv = *(const float4*)&Bs[kk][tx << 2];
            const float aa[4] = {Av.x, Av.y, Av.z, Av.w};
            const float bb[4] = {Bv.x, Bv.y, Bv.z, Bv.w};
#pragma unroll
            for (int i = 0; i < 4; ++i)
#pragma unroll
                for (int j = 0; j < 4; ++j)
                    c[i][j] = fmaf(aa[i], bb[j], c[i][j]);
        }
    }
    float* Cp = C + (size_t)(bm * BM + (ty << 2)) * N + bn * BN + (tx << 2);
#pragma unroll
    for (int i = 0; i < 4; ++i)
        *(float4*)(Cp + (size_t)i * N) =
            make_float4(c[i][0], c[i][1], c[i][2], c[i][3]);
}

// ---------------------------------------------------------------------------
// Causal depthwise conv (K=4) + SiLU.
// q -> qf (fp32), k -> kf (fp32), v -> vbuf (bf16).
// ---------------------------------------------------------------------------
__global__ __launch_bounds__(256) void conv_silu_kernel(
    const bf16* __restrict__ qkvz, const float* __restrict__ cw,
    float* __restrict__ qf, float* __restrict__ kf, bf16* __restrict__ vbuf) {
    const int64_t idx = (int64_t)blockIdx.x * 256 + threadIdx.x;
    const int c = (int)(idx & (CONV_DIM_ - 1));
    const int64_t bs = idx >> 13;
    const int s = (int)(bs & (S_ - 1));

    int col;
    if (c < KEY_DIM_) {
        col = ((c >> 7) * 768) + (c & 127);                       // q
    } else if (c < 2 * KEY_DIM_) {
        const int c2 = c - KEY_DIM_;
        col = ((c2 >> 7) * 768) + 128 + (c2 & 127);               // k
    } else {
        const int c3 = c - 2 * KEY_DIM_;
        col = ((c3 >> 8) * 768) + 256 + (c3 & 255);               // v
    }
    const float w0 = cw[c * 4 + 0], w1 = cw[c * 4 + 1];
    const float w2 = cw[c * 4 + 2], w3 = cw[c * 4 + 3];
    const bf16* xp = qkvz + bs * (int64_t)QKVZ_DIM_ + col;
    float acc = w3 * bf2f(xp[0]);
    if (s >= 1) acc = fmaf(w2, bf2f(xp[-QKVZ_DIM_]), acc);
    if (s >= 2) acc = fmaf(w1, bf2f(xp[-2 * QKVZ_DIM_]), acc);
    if (s >= 3) acc = fmaf(w0, bf2f(xp[-3 * QKVZ_DIM_]), acc);
    const float y = silu_f(acc);
    if (c < KEY_DIM_) {
        qf[bs * KEY_DIM_ + c] = y;
    } else if (c < 2 * KEY_DIM_) {
        kf[bs * KEY_DIM_ + (c - KEY_DIM_)] = y;
    } else {
        vbuf[bs * VAL_DIM_ + (c - 2 * KEY_DIM_)] = f2bf(y);
    }
}

// ---------------------------------------------------------------------------
// Pre-normalize q/k (fp32, in place): q *= DK^-0.5/||q||, k *= 1/||k||.
// One wave per (b,s,hk); lane covers 2 elems of each row.
// ---------------------------------------------------------------------------
__global__ __launch_bounds__(256) void normalize_qk_kernel(
    float* __restrict__ qf, float* __restrict__ kf) {
    const int wid = (blockIdx.x * 256 + threadIdx.x) >> 6;  // B*S*HK
    const int lane = threadIdx.x & 63;
    const int hk = wid & (HK_ - 1);
    const int64_t bs = wid >> 4;
    float* qp = qf + bs * KEY_DIM_ + hk * DK_ + lane * 2;
    float* kp = kf + bs * KEY_DIM_ + hk * DK_ + lane * 2;
    const f32x2 q = *(const f32x2*)qp;
    const f32x2 k = *(const f32x2*)kp;
    float qs = fmaf(q.x, q.x, q.y * q.y);
    float ks = fmaf(k.x, k.x, k.y * k.y);
#pragma unroll
    for (int m = 1; m < 64; m <<= 1) {
        qs += __shfl_xor(qs, m);
        ks += __shfl_xor(ks, m);
    }
    const float qsc = rsqrtf(qs + EPS_) * 0.08838834764831845f;  // DK^-0.5
    const float ksc = rsqrtf(ks + EPS_);
    *(f32x2*)qp = (f32x2){q.x * qsc, q.y * qsc};
    *(f32x2*)kp = (f32x2){k.x * ksc, k.y * ksc};
}

// ---------------------------------------------------------------------------
// Gate precompute: egbuf = exp(g), betabuf = sigmoid(b)
// ---------------------------------------------------------------------------
__global__ __launch_bounds__(256) void gate_kernel(
    const float* __restrict__ ba, const float* __restrict__ A_log,
    const float* __restrict__ dt_bias, float* __restrict__ egbuf,
    float* __restrict__ betabuf) {
    const int idx = blockIdx.x * 256 + threadIdx.x;   // B*S*HV
    const int hv = idx & (HV_ - 1);
    const int bs = idx >> 5;
    const int hk = hv >> 1, j = hv & 1;
    const float* p = ba + (size_t)bs * BA_DIM_ + hk * 4;
    const float bval = p[j];
    const float aval = p[2 + j];
    const float x = aval + dt_bias[hv];
    const float sp = (x > 20.f) ? x : log1pf(expf(x));
    egbuf[idx] = expf(-expf(A_log[hv]) * sp);
    betabuf[idx] = 1.f / (1.f + expf(-bval));
}

// ---------------------------------------------------------------------------
// Gated delta rule scan, pk-math edition. One wave per (b, hv, dv-block-of-4).
// fp32 q/k, pre-exp'd gates, DPP reduces, prefetch distance 2 (2x unrolled,
// named register sets — no runtime indexing).
// ---------------------------------------------------------------------------
__global__ __launch_bounds__(256) void delta_scan_kernel(
    const float* __restrict__ qf, const float* __restrict__ kf,
    const bf16* __restrict__ vbuf, const float* __restrict__ egbuf,
    const float* __restrict__ betabuf, bf16* __restrict__ core) {
    const int wid = (blockIdx.x * 256 + threadIdx.x) >> 6;  // 0..2047
    const int lane = threadIdx.x & 63;
    const int dvb = wid & 31;
    const int hv = (wid >> 5) & 31;
    const int b = wid >> 10;
    const int g = lane & 15;
    const int dvi = lane >> 4;
    const int dv = (dvb << 2) + dvi;
    const int hk = hv >> 1;

    const float* qbase = qf + (size_t)b * S_ * KEY_DIM_ + hk * DK_ + g * 8;
    const float* kbase = kf + (size_t)b * S_ * KEY_DIM_ + hk * DK_ + g * 8;
    const bf16* vbase = vbuf + (size_t)b * S_ * VAL_DIM_ + dv + hv * DV_;
    const float* egp = egbuf + (size_t)b * S_ * HV_ + hv;
    const float* bp = betabuf + (size_t)b * S_ * HV_ + hv;
    bf16* op = core + (size_t)b * S_ * VAL_DIM_ + hv * DV_ + dv;

    f32x2 st0 = {0.f, 0.f}, st1 = {0.f, 0.f};
    f32x2 st2 = {0.f, 0.f}, st3 = {0.f, 0.f};

    f32x4 qA[2], kA[2], qB[2], kB[2];
    float vvA, egA, btA, vvB, egB, btB;

#define LOADSET(Qv, Kv, VV, EG, BT, sidx)                                      \
    do {                                                                       \
        const size_t _ro = (size_t)(sidx)*KEY_DIM_;                            \
        Qv[0] = *(const f32x4*)(qbase + _ro);                                  \
        Qv[1] = *(const f32x4*)(qbase + _ro + 4);                              \
        Kv[0] = *(const f32x4*)(kbase + _ro);                                  \
        Kv[1] = *(const f32x4*)(kbase + _ro + 4);                              \
        VV = bf2f(vbase[(size_t)(sidx)*VAL_DIM_]);                             \
        EG = egp[(size_t)(sidx)*HV_];                                          \
        BT = bp[(size_t)(sidx)*HV_];                                           \
    } while (0)

#define STEP(Qv, Kv, VV, EG, BT, sidx)                                         \
    do {                                                                       \
        const f32x2 k0 = __builtin_shufflevector(Kv[0], Kv[0], 0, 1);          \
        const f32x2 k1 = __builtin_shufflevector(Kv[0], Kv[0], 2, 3);          \
        const f32x2 k2 = __builtin_shufflevector(Kv[1], Kv[1], 0, 1);          \
        const f32x2 k3 = __builtin_shufflevector(Kv[1], Kv[1], 2, 3);          \
        const f32x2 q0 = __builtin_shufflevector(Qv[0], Qv[0], 0, 1);          \
        const f32x2 q1 = __builtin_shufflevector(Qv[0], Qv[0], 2, 3);          \
        const f32x2 q2 = __builtin_shufflevector(Qv[1], Qv[1], 0, 1);          \
        const f32x2 q3 = __builtin_shufflevector(Qv[1], Qv[1], 2, 3);          \
        const f32x2 eg2 = {EG, EG};                                            \
        st0 = pk_mul(st0, eg2);                                                \
        st1 = pk_mul(st1, eg2);                                                \
        st2 = pk_mul(st2, eg2);                                                \
        st3 = pk_mul(st3, eg2);                                                \
        f32x2 pa = pk_mul(k0, st0);                                            \
        pa = pk_fma(k1, st1, pa);                                              \
        f32x2 pb = pk_mul(k2, st2);                                            \
        pb = pk_fma(k3, st3, pb);                                              \
        pa = pk_add(pa, pb);                                                   \
        float p = pa.x + pa.y;                                                 \
        p = row16_sum(p);                                                      \
        const float delta = (VV - p) * BT;                                     \
        const f32x2 d2 = {delta, delta};                                       \
        st0 = pk_fma(k0, d2, st0);                                             \
        st1 = pk_fma(k1, d2, st1);                                             \
        st2 = pk_fma(k2, d2, st2);                                             \
        st3 = pk_fma(k3, d2, st3);                                             \
        f32x2 oa = pk_mul(q0, st0);                                            \
        oa = pk_fma(q1, st1, oa);                                              \
        f32x2 ob = pk_mul(q2, st2);                                            \
        ob = pk_fma(q3, st3, ob);                                              \
        oa = pk_add(oa, ob);                                                   \
        float o = oa.x + oa.y;                                                 \
        o = row16_sum(o);                                                      \
        if (g == 0) op[(size_t)(sidx)*VAL_DIM_] = f2bf(o);                     \
    } while (0)

    LOADSET(qA, kA, vvA, egA, btA, 0);
    LOADSET(qB, kB, vvB, egB, btB, 1);

    for (int s = 0; s < S_; s += 2) {
        STEP(qA, kA, vvA, egA, btA, s);
        // prefetch s+2 into set A (benign 2-row overread at the tail; the
        // following ws buffers absorb it)
        LOADSET(qA, kA, vvA, egA, btA, s + 2);
        STEP(qB, kB, vvB, egB, btB, s + 1);
        LOADSET(qB, kB, vvB, egB, btB, s + 3);
    }
#undef LOADSET
#undef STEP
}

// ---------------------------------------------------------------------------
// Gated RMSNorm in-place on bf16 core; z from bf16 qkvz.
// ---------------------------------------------------------------------------
__global__ __launch_bounds__(256) void rmsnorm_gate_kernel(
    bf16* __restrict__ core, const bf16* __restrict__ qkvz,
    const float* __restrict__ nw) {
    const int wid = (blockIdx.x * 256 + threadIdx.x) >> 6;
    const int lane = threadIdx.x & 63;
    const int hv = wid & (HV_ - 1);
    const int64_t bs = wid >> 5;
    bf16* x = core + (size_t)bs * VAL_DIM_ + hv * DV_;
    const float x0 = bf2f(x[lane]);
    const float x1 = bf2f(x[lane + 64]);
    float ss = fmaf(x0, x0, x1 * x1);
#pragma unroll
    for (int m = 1; m < 64; m <<= 1) ss += __shfl_xor(ss, m);
    const float inv = rsqrtf(ss * (1.f / 128.f) + EPS_);
    const bf16* z =
        qkvz + (size_t)bs * QKVZ_DIM_ + (hv >> 1) * 768 + 512 + (hv & 1) * 128;
    x[lane] = f2bf(x0 * inv * nw[lane] * silu_f(bf2f(z[lane])));
    x[lane + 64] =
        f2bf(x1 * inv * nw[lane + 64] * silu_f(bf2f(z[lane + 64])));
}

// ---------------------------------------------------------------------------
extern "C" void kernel_launch(void* const* d_in, const int* in_sizes, int n_in,
                              void* d_out, int out_size, void* d_ws,
                              size_t ws_size, hipStream_t stream) {
    const float* hidden  = (const float*)d_in[0];
    const float* W_qkvz  = (const float*)d_in[1];
    const float* W_ba    = (const float*)d_in[2];
    const float* conv_w  = (const float*)d_in[3];
    const float* dt_bias = (const float*)d_in[4];
    const float* A_log   = (const float*)d_in[5];
    const float* norm_w  = (const float*)d_in[6];
    const float* W_out   = (const float*)d_in[7];
    float* out = (float*)d_out;

    // workspace: ~321.1 MB (< run-proven 337.5 MB; ws_size known < 404.75 MB)
    bf16* hidden_bf = (bf16*)d_ws;                        //  8,388,608 e
    bf16* Wq_bf  = hidden_bf + (size_t)8388608;           // 25,165,824 e
    bf16* Wo_bf  = Wq_bf + (size_t)25165824;              //  8,388,608 e
    bf16* qkvz   = Wo_bf + (size_t)8388608;               // 50,331,648 e
    float* qf    = (float*)(qkvz + (size_t)50331648);     //  8,388,608 f
    float* kf    = qf + (size_t)8388608;                  //  8,388,608 f
    bf16* vbuf   = (bf16*)(kf + (size_t)8388608);         // 16,777,216 e
    bf16* core   = vbuf + (size_t)16777216;               // 16,777,216 e
    float* ba      = (float*)(core + (size_t)16777216);   //    262,144 f
    float* egbuf   = ba + 262144;                         //    131,072 f
    float* betabuf = egbuf + 131072;                      //    131,072 f

    const int MBS = B_ * S_;  // 4096

    // 0. fp32 -> bf16 operand conversion
    f2bf_kernel<<<8388608 / 1024, 256, 0, stream>>>(hidden, hidden_bf);
    f2bf_kernel<<<25165824 / 1024, 256, 0, stream>>>(W_qkvz, Wq_bf);
    f2bf_kernel<<<8388608 / 1024, 256, 0, stream>>>(W_out, Wo_bf);

    // 1. qkvz = hidden @ W_qkvz^T (bf16 MFMA)
    gemm_mfma_nt<1><<<dim3(QKVZ_DIM_ / 128, MBS / 128), 256, 0, stream>>>(
        hidden_bf, Wq_bf, (void*)qkvz, MBS, QKVZ_DIM_, HID_);
    // 2. ba = hidden @ W_ba^T (fp32 vector)
    gemm_nt_f32<<<dim3(BA_DIM_ / BN, MBS / BM), 256, 0, stream>>>(
        hidden, W_ba, ba, MBS, BA_DIM_, HID_);
    // 3. gates (eg = exp(g))
    gate_kernel<<<(MBS * HV_) / 256, 256, 0, stream>>>(ba, A_log, dt_bias,
                                                       egbuf, betabuf);
    // 4. causal conv + silu -> qf/kf (fp32), vbuf (bf16)
    conv_silu_kernel<<<(int)(((int64_t)MBS * CONV_DIM_) / 256), 256, 0,
                       stream>>>(qkvz, conv_w, qf, kf, vbuf);
    // 4b. pre-normalize q/k in place (fp32)
    normalize_qk_kernel<<<(MBS * HK_ * 64) / 256, 256, 0, stream>>>(qf, kf);
    // 5. gated delta rule scan -> core (bf16)
    delta_scan_kernel<<<(B_ * HV_ * (DV_ / 4) * 64) / 256, 256, 0, stream>>>(
        qf, kf, vbuf, egbuf, betabuf, core);
    // 6. gated rmsnorm (in place on bf16 core)
    rmsnorm_gate_kernel<<<(MBS * HV_ * 64) / 256, 256, 0, stream>>>(core, qkvz,
                                                                    norm_w);
    // 7. out = core @ W_out^T (bf16 MFMA -> fp32 out)
    gemm_mfma_nt<0><<<dim3(HID_ / 128, MBS / 128), 256, 0, stream>>>(
        core, Wo_bf, (void*)out, MBS, HID_, VAL_DIM_);
}